// Round 4
// baseline (15.339 us; speedup 1.0000x reference)
//
#include <hip/hip_runtime.h>
#include <math.h>

#define NB 256
#define NN 2048
#define NE 128
#define NORMC 0.08838834764831845f   // 1/sqrt(128)

// ---- table row layout in d_ws (47 rows x 128 floats) ----
// 0-2  Qc_n  3 bQ1_n   4-5 Qc_d   6 bQ1_d      (Wn@wq1 / bn@wq1 / Wd@wq1 / bd@wq1)
// 7-9  Qn_n 10 bQ2_n  11-12 Qn_d 13 bQ2_d      (wq2)
// 14-17 Qs  18 bQ3                             (Ws@wq3 / bs@wq3)
// 19-21 Kc_n 22 bKc_n 23-24 Kc_d 25 bKc_d      (wk1)
// 26-28 Ak  29 ck     30-31 Dk   32 dk         (wk2)
// 33-35 Vc_n 36 bVc_n 37-38 Vc_d 39 bVc_d      (wv1)
// 40-42 Av  43 cv     44-45 Dv   46 dv         (wv2)

__global__ __launch_bounds__(1024)
void k1_tables(const float* __restrict__ Wn, const float* __restrict__ bn,
               const float* __restrict__ Wd, const float* __restrict__ bd,
               const float* __restrict__ Ws, const float* __restrict__ bs,
               const float* __restrict__ wq, const float* __restrict__ wk,
               const float* __restrict__ wv, const float* __restrict__ nodef,
               const void* __restrict__ maskp, float* __restrict__ T)
{
  const int b = blockIdx.x, t = threadIdx.x;
  if (b < 7) {
    __shared__ float sW[128 * 128];     // 64 KB: one right-matrix slice
    __shared__ float sLv[7 * 128];      // left vectors
    const float* mat; int rowbase;
    switch (b) {
      case 0: mat = wq;          rowbase = 0;  break;
      case 1: mat = wq + 16384;  rowbase = 7;  break;
      case 2: mat = wq + 32768;  rowbase = 14; break;
      case 3: mat = wk;          rowbase = 19; break;
      case 4: mat = wk + 16384;  rowbase = 26; break;
      case 5: mat = wv;          rowbase = 33; break;
      default: mat = wv + 16384; rowbase = 40; break;
    }
    const int nrows = (b == 2) ? 5 : 7;
    // stage the 128x128 matrix (4 float4 per thread, coalesced)
    {
      const float4* s4 = (const float4*)mat;
      float4* d4 = (float4*)sW;
      #pragma unroll
      for (int i = 0; i < 4; ++i) d4[t + i * 1024] = s4[t + i * 1024];
    }
    // stage left vectors (row r at sLv[r*128])
    if (b == 2) {
      if (t < 512)      sLv[t] = Ws[t];
      else if (t < 640) sLv[t] = bs[t - 512];
    } else {
      if (t < 384)      sLv[t] = Wn[t];
      else if (t < 512) sLv[t] = bn[t - 384];
      else if (t < 768) sLv[t] = Wd[t - 512];
      else if (t < 896) sLv[t] = bd[t - 768];
    }
    __syncthreads();
    const int r = t >> 7, e = t & 127;
    if (r < nrows) {
      float acc = 0.f;
      #pragma unroll 16
      for (int j = 0; j < 128; ++j) acc += sLv[r * 128 + j] * sW[j * 128 + e];
      T[(rowbase + r) * NE + e] = acc;
    }
  } else {
    // ---- L3 warmers: touch node_feats (6.29 MB) + first 512 KB of mask
    const float4* nf4 = (const float4*)nodef;
    float fs = 0.f;
    for (int i = (b - 7) * 1024 + t; i < NB * NN * 3 / 4; i += 249 * 1024) {
      float4 v = nf4[i];
      fs += v.x + v.y + v.z + v.w;
    }
    const uint4* mu = (const uint4*)maskp;
    unsigned int ms = 0;
    for (int i = (b - 7) * 1024 + t; i < 32768; i += 249 * 1024) {
      uint4 v = mu[i];
      ms |= v.x | v.y | v.z | v.w;
    }
    asm volatile("" :: "v"(fs), "v"(ms));   // keep loads live, no DCE
  }
}

__global__ __launch_bounds__(512)
void k2_main(const float* __restrict__ nodef,   // [B,N,3]
             const float* __restrict__ state,   // [B,4]
             const int*   __restrict__ curr_id,
             const int*   __restrict__ next_id,
             const void*  __restrict__ maskp,
             const float* __restrict__ T,
             float* __restrict__ out)           // [B,128]
{
  const int b = blockIdx.x, t = threadIdx.x;
  const int w = t >> 6, l = t & 63;

  __shared__ float scal[8];
  __shared__ float redm[8], redsum[4][8];
  __shared__ float sse0;

  // ---- node feats: 4 nodes/thread (12 floats = 3 float4, contiguous)
  const float4* A4 = (const float4*)(nodef + (size_t)b * (NN * 3));
  const float4 a0 = A4[3 * t], a1 = A4[3 * t + 1], a2 = A4[3 * t + 2];

  // ---- per-batch scalars (gather chain: id load -> coord load)
  const int cid = curr_id[b], nid = next_id[b];
  const float4 st4 = *(const float4*)(state + b * 4);
  const float* xcp = nodef + ((size_t)b * NN + cid) * 3;
  const float* xnp = nodef + ((size_t)b * NN + nid) * 3;
  const float xc0 = xcp[0], xc1 = xcp[1], xc2 = xcp[2];
  const float xn0 = xnp[0], xn1 = xnp[1], xn2 = xnp[2];
  const float nf00 = nodef[(size_t)b * NN * 3];
  const float nf01 = nodef[(size_t)b * NN * 3 + 1];

  // ---- mask width detect: per-wave ballot over first 8 KB, no sync needed
  int mflag;
  {
    const longlong2 mv = ((const longlong2*)maskp)[t];
    const unsigned int w0 = (unsigned int)mv.x, w1 = (unsigned int)((unsigned long long)mv.x >> 32);
    const unsigned int w2 = (unsigned int)mv.y, w3 = (unsigned int)((unsigned long long)mv.y >> 32);
    int f = 0;
    if ((w0 | w1 | w2 | w3) & 0xFFFFFF00u) f |= 1;   // nonzero sub-word byte -> byte mask
    if ((w1 & 0xFFu) | (w3 & 0xFFu))       f |= 2;   // odd 32-bit word LSB -> int32 mask
    const unsigned long long B1 = __ballot(f & 1);
    const unsigned long long B2 = __ballot(f & 2);
    mflag = B1 ? 1 : (B2 ? 2 : 4);
  }

  // ---- mask for 4 nodes (vectorized per width)
  int mk0, mk1, mk2, mk3;
  {
    const size_t off = (size_t)b * NN + 4 * (size_t)t;
    if (mflag == 1) {
      const unsigned int mm = *(const unsigned int*)((const unsigned char*)maskp + off);
      mk0 = mm & 0xFF; mk1 = (mm >> 8) & 0xFF; mk2 = (mm >> 16) & 0xFF; mk3 = (mm >> 24) & 0xFF;
    } else if (mflag == 2) {
      const int4 mm = *(const int4*)((const int*)maskp + off);
      mk0 = mm.x; mk1 = mm.y; mk2 = mm.z; mk3 = mm.w;
    } else {
      const longlong2* mp = (const longlong2*)maskp;
      const longlong2 u = mp[off / 2], v = mp[off / 2 + 1];
      mk0 = u.x != 0; mk1 = u.y != 0; mk2 = v.x != 0; mk3 = v.y != 0;
    }
  }

  // ---- epilogue columns (t<128): load early, consume at the end
  float evc = 0.f, eav0 = 0.f, eav1 = 0.f, eav2 = 0.f, ecv = 0.f, edv0 = 0.f, edv1 = 0.f, edv = 0.f;
  if (t < NE) {
    const int e = t;
    const float vn0 = T[33*NE+e], vn1 = T[34*NE+e], vn2 = T[35*NE+e], vn3 = T[36*NE+e];
    const float vd0 = T[37*NE+e], vd1 = T[38*NE+e], vd2 = T[39*NE+e];
    evc = (cid == 0) ? (xc0*vd0 + xc1*vd1 + vd2)
                     : (xc0*vn0 + xc1*vn1 + xc2*vn2 + vn3);
    eav0 = T[40*NE+e]; eav1 = T[41*NE+e]; eav2 = T[42*NE+e]; ecv = T[43*NE+e];
    edv0 = T[44*NE+e]; edv1 = T[45*NE+e]; edv  = T[46*NE+e];
  }

  // ---- every wave materializes q for e=l and e=l+64 (both id-variants loaded)
  float qh[2];
  #pragma unroll
  for (int h = 0; h < 2; ++h) {
    const int e = l + 64 * h;
    const float cn0 = T[0*NE+e], cn1 = T[1*NE+e], cn2 = T[2*NE+e], cn3 = T[3*NE+e];
    const float cd0 = T[4*NE+e], cd1 = T[5*NE+e], cd2 = T[6*NE+e];
    const float nn0 = T[7*NE+e], nn1 = T[8*NE+e], nn2 = T[9*NE+e], nn3 = T[10*NE+e];
    const float nd0 = T[11*NE+e], nd1 = T[12*NE+e], nd2 = T[13*NE+e];
    const float s0 = T[14*NE+e], s1 = T[15*NE+e], s2 = T[16*NE+e], s3 = T[17*NE+e], s4 = T[18*NE+e];
    float q = (cid == 0) ? (xc0*cd0 + xc1*cd1 + cd2)
                         : (xc0*cn0 + xc1*cn1 + xc2*cn2 + cn3);
    q += (nid == 0) ? (xn0*nd0 + xn1*nd1 + nd2)
                    : (xn0*nn0 + xn1*nn1 + xn2*nn2 + nn3);
    q += st4.x*s0 + st4.y*s1 + st4.z*s2 + st4.w*s3 + s4;
    qh[h] = q;
  }

  // ---- wave w computes scalar w: {q.kc, q.ck, q.dk, Ak@q x3, Dk@q x2}
  {
    float tgl, tgh;
    if (w == 0) {
      #pragma unroll
      for (int h = 0; h < 2; ++h) {
        const int e = l + 64 * h;
        const float kn0 = T[19*NE+e], kn1 = T[20*NE+e], kn2 = T[21*NE+e], kn3 = T[22*NE+e];
        const float kd0 = T[23*NE+e], kd1 = T[24*NE+e], kd2 = T[25*NE+e];
        const float kc = (cid == 0) ? (xc0*kd0 + xc1*kd1 + kd2)
                                    : (xc0*kn0 + xc1*kn1 + xc2*kn2 + kn3);
        if (h == 0) tgl = kc; else tgh = kc;
      }
    } else {
      const int row = (w == 1) ? 29 : (w == 2) ? 32 : (w <= 5) ? (23 + w) : (24 + w);
      tgl = T[row*NE + l]; tgh = T[row*NE + 64 + l];
    }
    float p = qh[0] * tgl + qh[1] * tgh;
    #pragma unroll
    for (int o = 32; o; o >>= 1) p += __shfl_down(p, o, 64);
    if (l == 0) scal[w] = p;
  }
  __syncthreads();   // sync A: scal published

  const float qkc = scal[0], qck = scal[1], qdk = scal[2];
  const float gk0 = scal[3], gk1 = scal[4], gk2 = scal[5];
  const float gdk0 = scal[6], gdk1 = scal[7];

  // ---- compat for 4 register-resident nodes + block max
  const float f0 = a0.x, f1 = a0.y, f2 = a0.z, f3 = a0.w;
  const float f4 = a1.x, f5 = a1.y, f6 = a1.z, f7 = a1.w;
  const float f8 = a2.x, f9 = a2.y, f10 = a2.z, f11 = a2.w;
  float c0, c1, c2, c3;
  if (t == 0) c0 = qkc + qdk + f0*gdk0 + f1*gdk1;           // node 0 = depot
  else        c0 = qkc + qck + f0*gk0 + f1*gk1 + f2*gk2;
  c1 = qkc + qck + f3*gk0 + f4*gk1 + f5*gk2;
  c2 = qkc + qck + f6*gk0 + f7*gk1 + f8*gk2;
  c3 = qkc + qck + f9*gk0 + f10*gk1 + f11*gk2;
  c0 = mk0 ? c0 * NORMC : -INFINITY;
  c1 = mk1 ? c1 * NORMC : -INFINITY;
  c2 = mk2 ? c2 * NORMC : -INFINITY;
  c3 = mk3 ? c3 * NORMC : -INFINITY;

  float lmax = fmaxf(fmaxf(c0, c1), fmaxf(c2, c3));
  #pragma unroll
  for (int o = 32; o; o >>= 1) lmax = fmaxf(lmax, __shfl_down(lmax, o, 64));
  if (l == 0) redm[w] = lmax;
  __syncthreads();   // sync B: max published
  float m = redm[0];
  #pragma unroll
  for (int i = 1; i < 8; ++i) m = fmaxf(m, redm[i]);

  // ---- exp + denom + 3-component weighted feature sums (n>=1)
  const float e0 = __expf(c0 - m), e1 = __expf(c1 - m);
  const float e2 = __expf(c2 - m), e3 = __expf(c3 - m);
  if (t == 0) sse0 = e0;
  float le = e0 + e1 + e2 + e3;
  float s0, s1, s2;
  if (t == 0) { s0 = 0.f; s1 = 0.f; s2 = 0.f; }             // exclude depot node
  else        { s0 = e0*f0; s1 = e0*f1; s2 = e0*f2; }
  s0 += e1*f3 + e2*f6 + e3*f9;
  s1 += e1*f4 + e2*f7 + e3*f10;
  s2 += e1*f5 + e2*f8 + e3*f11;
  #pragma unroll
  for (int o = 32; o; o >>= 1) {
    le += __shfl_down(le, o, 64);
    s0 += __shfl_down(s0, o, 64);
    s1 += __shfl_down(s1, o, 64);
    s2 += __shfl_down(s2, o, 64);
  }
  if (l == 0) { redsum[0][w] = le; redsum[1][w] = s0; redsum[2][w] = s1; redsum[3][w] = s2; }
  __syncthreads();   // sync C: sums + sse0 published

  // ---- epilogue on t<128
  if (t < NE) {
    float L = 0.f, S0 = 0.f, S1 = 0.f, S2 = 0.f;
    #pragma unroll
    for (int i = 0; i < 8; ++i) {
      L += redsum[0][i]; S0 += redsum[1][i]; S1 += redsum[2][i]; S2 += redsum[3][i];
    }
    const float a0w = sse0 / L;
    const float hv = evc
      + (1.0f - a0w) * ecv
      + (S0*eav0 + S1*eav1 + S2*eav2) / L
      + a0w * (nf00*edv0 + nf01*edv1 + edv);
    out[(size_t)b * NE + t] = hv;
  }
}

extern "C" void kernel_launch(void* const* d_in, const int* in_sizes, int n_in,
                              void* d_out, int out_size, void* d_ws, size_t ws_size,
                              hipStream_t stream) {
  (void)in_sizes; (void)n_in; (void)out_size; (void)ws_size;
  const float* nodef   = (const float*)d_in[0];
  const float* state   = (const float*)d_in[1];
  const float* W_node  = (const float*)d_in[2];
  const float* b_node  = (const float*)d_in[3];
  const float* W_depot = (const float*)d_in[4];
  const float* b_depot = (const float*)d_in[5];
  const float* W_state = (const float*)d_in[6];
  const float* b_state = (const float*)d_in[7];
  const float* w_q     = (const float*)d_in[8];
  const float* w_k     = (const float*)d_in[9];
  const float* w_v     = (const float*)d_in[10];
  const int*   curr_id = (const int*)d_in[11];
  const int*   next_id = (const int*)d_in[12];
  const void*  maskp   = d_in[13];
  float* T   = (float*)d_ws;
  float* out = (float*)d_out;

  hipLaunchKernelGGL(k1_tables, dim3(256), dim3(1024), 0, stream,
                     W_node, b_node, W_depot, b_depot, W_state, b_state,
                     w_q, w_k, w_v, nodef, maskp, T);
  hipLaunchKernelGGL(k2_main, dim3(NB), dim3(512), 0, stream,
                     nodef, state, curr_id, next_id, maskp, T, out);
}